// Round 6
// baseline (291.472 us; speedup 1.0000x reference)
//
#include <hip/hip_runtime.h>
#include <hip/hip_bf16.h>
#include <math.h>

#define T_DIM 4096
#define D_DIM 64
#define SPLITS 8
#define SCALE_X 14.4269504088896340736f   // (1/TEMPERATURE) * log2(e): exp(10 s) = exp2(14.427 s)
#define LN2 0.69314718055994530942f

typedef short bfrag8 __attribute__((ext_vector_type(8)));   // 8 bf16 = 4 VGPRs
typedef float floatx4 __attribute__((ext_vector_type(4)));

__device__ __forceinline__ float bf2f(unsigned short u) {
    return __uint_as_float(((unsigned int)u) << 16);
}

// ---------------------------------------------------------------------------
// K1 "prep": fused normalize (blocks [0,normBlocks)) + parallel 2-pass mask
// compaction + gsum/done/out zeroing (blocks [normBlocks, normBlocks+2B)).
// Normalize: 16 rows/block, 16 lanes/row, float4 loads, ushort4 stores.
// x rows scaled by SCALE_X (folds 1/T and log2(e) into the bf16 cast).
// ---------------------------------------------------------------------------
__launch_bounds__(256)
__global__ void prep(const float* __restrict__ x, const float* __restrict__ y,
                     const int* __restrict__ im1, const int* __restrict__ sh1,
                     const int* __restrict__ im2, const int* __restrict__ sh2,
                     __hip_bfloat16* __restrict__ xn, __hip_bfloat16* __restrict__ yn,
                     int* __restrict__ Ridx, int* __restrict__ Cidx,
                     int* __restrict__ cnt, float* __restrict__ gsum,
                     int* __restrict__ done, float* __restrict__ out,
                     int rows, int normBlocks, int B) {
    int tid = threadIdx.x;
    if ((int)blockIdx.x < normBlocks) {
        int row = blockIdx.x * 16 + (tid >> 4);
        int l = tid & 15;
        const float* src; __hip_bfloat16* dst; float scale;
        if (row < rows) { src = x; dst = xn; scale = SCALE_X; }
        else { src = y; dst = yn; scale = 1.0f; row -= rows; }
        size_t off = (size_t)row * D_DIM + l * 4;
        float4 v = *reinterpret_cast<const float4*>(src + off);
        float ss = v.x * v.x + v.y * v.y + v.z * v.z + v.w * v.w;
        #pragma unroll
        for (int o = 1; o < 16; o <<= 1) ss += __shfl_xor(ss, o);
        float inv = scale / fmaxf(sqrtf(ss), 1e-12f);
        __hip_bfloat16 h0 = __float2bfloat16(v.x * inv);
        __hip_bfloat16 h1 = __float2bfloat16(v.y * inv);
        __hip_bfloat16 h2 = __float2bfloat16(v.z * inv);
        __hip_bfloat16 h3 = __float2bfloat16(v.w * inv);
        ushort4 o4;
        o4.x = *reinterpret_cast<unsigned short*>(&h0);
        o4.y = *reinterpret_cast<unsigned short*>(&h1);
        o4.z = *reinterpret_cast<unsigned short*>(&h2);
        o4.w = *reinterpret_cast<unsigned short*>(&h3);
        *reinterpret_cast<ushort4*>((unsigned short*)dst + off) = o4;
    } else {
        int z = blockIdx.x - normBlocks;
        int which = z & 1, b = z >> 1;
        const int* im = which ? im2 : im1;
        const int* sh = which ? sh2 : sh1;
        int* idxout   = which ? Cidx : Ridx;

        // 64 wave-units of 64 elements; wave w owns units w, w+4, ..., w+60.
        __shared__ int cw[64];     // per-unit selected count
        __shared__ int offx[64];   // exclusive prefix
        int w = tid >> 6, lane = tid & 63;
        const int* imb = im + (size_t)b * T_DIM;
        const int* shb = sh + (size_t)b * T_DIM;

        // pass 1: parallel counts
        #pragma unroll
        for (int k = 0; k < 16; k++) {
            int u = w + k * 4;
            int t = u * 64 + lane;
            int mv = imb[t] * shb[t];
            unsigned long long bal = __ballot(mv != 0);
            if (lane == 0) cw[u] = __popcll(bal);
        }
        __syncthreads();
        // scan 64 counts on wave 0
        if (w == 0) {
            int v = cw[lane];
            int incl = v;
            #pragma unroll
            for (int o = 1; o < 64; o <<= 1) {
                int t = __shfl_up(incl, o);
                if (lane >= o) incl += t;
            }
            offx[lane] = incl - v;
            if (lane == 63) cnt[which * B + b] = incl;
        }
        __syncthreads();
        // pass 2: parallel writes
        #pragma unroll
        for (int k = 0; k < 16; k++) {
            int u = w + k * 4;
            int t = u * 64 + lane;
            int mv = imb[t] * shb[t];
            unsigned long long bal = __ballot(mv != 0);
            int pre = __popcll(bal & ((1ull << lane) - 1ull));
            if (mv) idxout[(size_t)b * T_DIM + offx[u] + pre] = t;
        }
        // zero gsum + done for this batch (which==0 blocks) + out
        if (which == 0) {
            for (int i = tid; i < T_DIM; i += 256) gsum[(size_t)b * T_DIM + i] = 0.0f;
            if (tid < 64) done[b * 64 + tid] = 0;
            if (b == 0 && tid == 0) out[0] = 0.0f;
        }
    }
}

// ---------------------------------------------------------------------------
// K2 main: grid (T/64 col-tiles, B, SPLITS); 256 thr / 4 waves.
// Gathers ONLY selected rows via Ridx: gsum[c] += sum_{i<nx} exp2(sim2[R_i][c]),
// sim2 in log2 units (scale folded into xn). Two-level prefetch; tail rows
// masked by in-reg weights. FUSED FINALIZE: the last of the SPLITS blocks per
// (b, col-tile) — tracked by a device-scope done counter — reads its 64
// columns of gsum (agent-scope atomic loads), computes diag dots, and
// atomicAdds LN2*(log2(g)-d)/(m*B) into out[0]. No ordering assumption:
// nobody waits; the last arriver (any dispatch order) finishes the tile.
// ---------------------------------------------------------------------------
__launch_bounds__(256)
__global__ void ntxent_main(const __hip_bfloat16* __restrict__ xn,
                            const __hip_bfloat16* __restrict__ yn,
                            const int* __restrict__ Ridx,
                            const int* __restrict__ Cidx,
                            const int* __restrict__ cnt,
                            float* __restrict__ gsum,
                            int* __restrict__ done,
                            float* __restrict__ out, int B) {
    int b  = blockIdx.y;
    int nx = cnt[b];
    int ny = cnt[B + b];
    int m  = min(nx, ny);
    int j0 = blockIdx.x * 64;
    if (j0 >= m) return;
    int rbase = blockIdx.z * 64;          // row stride 64*SPLITS = 512 selected rows

    __shared__ __hip_bfloat16 Bs[64 * 72];   // col-vector stride 144B
    __shared__ int Cloc[64];

    int tid  = threadIdx.x;
    int wave = tid >> 6, lane = tid & 63, quad = lane >> 4, c16 = lane & 15;

    if (tid < 64) {
        int j = j0 + tid;
        Cloc[tid] = (j < ny) ? Cidx[(size_t)b * T_DIM + j] : 0;
    }
    __syncthreads();

    // Stage B tile: 64 col vectors x 128B
    #pragma unroll
    for (int i = tid; i < 64 * 8; i += 256) {
        int c = i >> 3, part = i & 7;
        bfrag8 v = *reinterpret_cast<const bfrag8*>(
            yn + ((size_t)b * T_DIM + Cloc[c]) * D_DIM + part * 8);
        *reinterpret_cast<bfrag8*>(&Bs[c * 72 + part * 8]) = v;
    }
    __syncthreads();

    bfrag8 bf[4][2];
    #pragma unroll
    for (int cg = 0; cg < 4; cg++)
        #pragma unroll
        for (int kh = 0; kh < 2; kh++)
            bf[cg][kh] = *reinterpret_cast<const bfrag8*>(
                &Bs[(cg * 16 + c16) * 72 + kh * 32 + quad * 8]);

    const __hip_bfloat16* xb = xn + (size_t)b * T_DIM * D_DIM;
    const __hip_bfloat16* yb = yn + (size_t)b * T_DIM * D_DIM;
    const int* Rb = Ridx + (size_t)b * T_DIM;
    const int* Cb = Cidx + (size_t)b * T_DIM;

    float csum[4] = {0.f, 0.f, 0.f, 0.f};

    // prefetch iter 0: index then row (tail rows use row 0, weight 0)
    int gi = rbase + wave * 16 + c16;
    int idx0 = (gi < nx) ? Rb[gi] : 0;
    const __hip_bfloat16* arow = xb + (size_t)idx0 * D_DIM;
    bfrag8 af0 = *reinterpret_cast<const bfrag8*>(arow + quad * 8);
    bfrag8 af1 = *reinterpret_cast<const bfrag8*>(arow + 32 + quad * 8);

    for (int i0 = rbase; i0 < nx; i0 += 64 * SPLITS) {
        int gin = i0 + 64 * SPLITS + wave * 16 + c16;
        int idxn = (gin < nx) ? Rb[gin] : 0;
        const __hip_bfloat16* narow = xb + (size_t)idxn * D_DIM;
        bfrag8 naf0 = *reinterpret_cast<const bfrag8*>(narow + quad * 8);
        bfrag8 naf1 = *reinterpret_cast<const bfrag8*>(narow + 32 + quad * 8);

        int grow0 = i0 + wave * 16 + quad * 4;
        float wv[4];
        #pragma unroll
        for (int r = 0; r < 4; r++) wv[r] = (grow0 + r < nx) ? 1.0f : 0.0f;

        #pragma unroll
        for (int cg = 0; cg < 4; cg++) {
            floatx4 acc = {0.f, 0.f, 0.f, 0.f};
            acc = __builtin_amdgcn_mfma_f32_16x16x32_bf16(af0, bf[cg][0], acc, 0, 0, 0);
            acc = __builtin_amdgcn_mfma_f32_16x16x32_bf16(af1, bf[cg][1], acc, 0, 0, 0);
            #pragma unroll
            for (int r = 0; r < 4; r++)
                csum[cg] += wv[r] * exp2f(acc[r]);
        }
        af0 = naf0; af1 = naf1;
    }

    // reduce over quads (rows): lanes differing in bits 4,5 hold same column
    #pragma unroll
    for (int cg = 0; cg < 4; cg++) {
        csum[cg] += __shfl_xor(csum[cg], 16);
        csum[cg] += __shfl_xor(csum[cg], 32);
    }
    if (lane < 16) {
        #pragma unroll
        for (int cg = 0; cg < 4; cg++)
            atomicAdd(&gsum[(size_t)b * T_DIM + j0 + cg * 16 + c16], csum[cg]);
    }

    // ---- fused finalize: last split-block for this (b, tile) ----
    __threadfence();               // release: gsum atomics visible device-wide
    __syncthreads();               // all 4 waves' atomics issued+fenced
    __shared__ int amLast;
    if (tid == 0) {
        int old = atomicAdd(&done[b * 64 + blockIdx.x], 1);
        amLast = (old == SPLITS - 1);
    }
    __syncthreads();
    if (!amLast) return;
    __threadfence();               // acquire side

    int g = tid >> 4, l = tid & 15;
    float acc = 0.0f;
    #pragma unroll
    for (int rep = 0; rep < 4; rep++) {
        int j = j0 + g + rep * 16;
        if (j < m) {
            int rj = Rb[j];
            int cj = Cb[j];
            const unsigned short* xa = (const unsigned short*)(xb + (size_t)rj * D_DIM) + l * 4;
            const unsigned short* yc = (const unsigned short*)(yb + (size_t)cj * D_DIM) + l * 4;
            float d = 0.0f;
            #pragma unroll
            for (int e = 0; e < 4; e++) d += bf2f(xa[e]) * bf2f(yc[e]);
            #pragma unroll
            for (int o = 1; o < 16; o <<= 1) d += __shfl_xor(d, o);
            if (l == 0) {
                float gv = __hip_atomic_load(&gsum[(size_t)b * T_DIM + j],
                                             __ATOMIC_ACQUIRE, __HIP_MEMORY_SCOPE_AGENT);
                acc += LN2 * (__log2f(gv) - d);
            }
        }
    }
    #pragma unroll
    for (int o = 1; o < 64; o <<= 1) acc += __shfl_xor(acc, o);
    __shared__ float ws2[4];
    if (lane == 0) ws2[wave] = acc;
    __syncthreads();
    if (tid == 0)
        atomicAdd(out, (ws2[0] + ws2[1] + ws2[2] + ws2[3]) / ((float)m * (float)B));
}

extern "C" void kernel_launch(void* const* d_in, const int* in_sizes, int n_in,
                              void* d_out, int out_size, void* d_ws, size_t ws_size,
                              hipStream_t stream) {
    const float* x  = (const float*)d_in[0];
    const float* y  = (const float*)d_in[1];
    const int* im1  = (const int*)d_in[2];
    const int* im2  = (const int*)d_in[3];
    const int* sh1  = (const int*)d_in[4];
    const int* sh2  = (const int*)d_in[5];

    int B = in_sizes[2] / T_DIM;
    int rows = B * T_DIM;
    size_t nElem = (size_t)rows * D_DIM;

    __hip_bfloat16* xn = (__hip_bfloat16*)d_ws;
    __hip_bfloat16* yn = xn + nElem;
    float* gsum = (float*)(yn + nElem);
    int*   Ridx = (int*)(gsum + rows);
    int*   Cidx = Ridx + rows;
    int*   cnt  = Cidx + rows;              // 2*B ints
    int*   done = cnt + 2 * B;              // B*64 ints

    int normBlocks = 2 * rows / 16;
    prep<<<normBlocks + 2 * B, 256, 0, stream>>>(x, y, im1, sh1, im2, sh2,
                                                 xn, yn, Ridx, Cidx, cnt,
                                                 gsum, done, (float*)d_out,
                                                 rows, normBlocks, B);

    dim3 grid(T_DIM / 64, B, SPLITS);
    ntxent_main<<<grid, 256, 0, stream>>>(xn, yn, Ridx, Cidx, cnt, gsum, done,
                                          (float*)d_out, B);
}

// Round 7
// 116.512 us; speedup vs baseline: 2.5016x; 2.5016x over previous
//
#include <hip/hip_runtime.h>
#include <hip/hip_bf16.h>
#include <math.h>

#define T_DIM 4096
#define D_DIM 64
#define SCALE_X 14.4269504088896340736f   // (1/TEMPERATURE) * log2(e): exp(10 s) = exp2(14.427 s)
#define LN2 0.69314718055994530942f

typedef short bfrag8 __attribute__((ext_vector_type(8)));   // 8 bf16 = 4 VGPRs
typedef float floatx4 __attribute__((ext_vector_type(4)));

__device__ __forceinline__ float bf2f(unsigned short u) {
    return __uint_as_float(((unsigned int)u) << 16);
}

// ---------------------------------------------------------------------------
// K1 "prep": fused normalize (blocks [0,normBlocks)) + parallel 2-pass mask
// compaction + out zeroing (blocks [normBlocks, normBlocks+2B)).
// Normalize: 16 rows/block, 16 lanes/row, float4 loads, ushort4 stores.
// x rows scaled by SCALE_X (folds 1/T and log2(e) into the bf16 cast).
// ---------------------------------------------------------------------------
__launch_bounds__(256)
__global__ void prep(const float* __restrict__ x, const float* __restrict__ y,
                     const int* __restrict__ im1, const int* __restrict__ sh1,
                     const int* __restrict__ im2, const int* __restrict__ sh2,
                     __hip_bfloat16* __restrict__ xn, __hip_bfloat16* __restrict__ yn,
                     int* __restrict__ Ridx, int* __restrict__ Cidx,
                     int* __restrict__ cnt, float* __restrict__ out,
                     int rows, int normBlocks, int B) {
    int tid = threadIdx.x;
    if ((int)blockIdx.x < normBlocks) {
        int row = blockIdx.x * 16 + (tid >> 4);
        int l = tid & 15;
        const float* src; __hip_bfloat16* dst; float scale;
        if (row < rows) { src = x; dst = xn; scale = SCALE_X; }
        else { src = y; dst = yn; scale = 1.0f; row -= rows; }
        size_t off = (size_t)row * D_DIM + l * 4;
        float4 v = *reinterpret_cast<const float4*>(src + off);
        float ss = v.x * v.x + v.y * v.y + v.z * v.z + v.w * v.w;
        #pragma unroll
        for (int o = 1; o < 16; o <<= 1) ss += __shfl_xor(ss, o);
        float inv = scale / fmaxf(sqrtf(ss), 1e-12f);
        __hip_bfloat16 h0 = __float2bfloat16(v.x * inv);
        __hip_bfloat16 h1 = __float2bfloat16(v.y * inv);
        __hip_bfloat16 h2 = __float2bfloat16(v.z * inv);
        __hip_bfloat16 h3 = __float2bfloat16(v.w * inv);
        ushort4 o4;
        o4.x = *reinterpret_cast<unsigned short*>(&h0);
        o4.y = *reinterpret_cast<unsigned short*>(&h1);
        o4.z = *reinterpret_cast<unsigned short*>(&h2);
        o4.w = *reinterpret_cast<unsigned short*>(&h3);
        *reinterpret_cast<ushort4*>((unsigned short*)dst + off) = o4;
    } else {
        int z = blockIdx.x - normBlocks;
        int which = z & 1, b = z >> 1;
        const int* im = which ? im2 : im1;
        const int* sh = which ? sh2 : sh1;
        int* idxout   = which ? Cidx : Ridx;

        // 64 wave-units of 64 elements; wave w owns units w, w+4, ..., w+60.
        __shared__ int cw[64];     // per-unit selected count
        __shared__ int offx[64];   // exclusive prefix
        int w = tid >> 6, lane = tid & 63;
        const int* imb = im + (size_t)b * T_DIM;
        const int* shb = sh + (size_t)b * T_DIM;

        // pass 1: parallel counts
        #pragma unroll
        for (int k = 0; k < 16; k++) {
            int u = w + k * 4;
            int t = u * 64 + lane;
            int mv = imb[t] * shb[t];
            unsigned long long bal = __ballot(mv != 0);
            if (lane == 0) cw[u] = __popcll(bal);
        }
        __syncthreads();
        // scan 64 counts on wave 0
        if (w == 0) {
            int v = cw[lane];
            int incl = v;
            #pragma unroll
            for (int o = 1; o < 64; o <<= 1) {
                int t = __shfl_up(incl, o);
                if (lane >= o) incl += t;
            }
            offx[lane] = incl - v;
            if (lane == 63) cnt[which * B + b] = incl;
        }
        __syncthreads();
        // pass 2: parallel writes
        #pragma unroll
        for (int k = 0; k < 16; k++) {
            int u = w + k * 4;
            int t = u * 64 + lane;
            int mv = imb[t] * shb[t];
            unsigned long long bal = __ballot(mv != 0);
            int pre = __popcll(bal & ((1ull << lane) - 1ull));
            if (mv) idxout[(size_t)b * T_DIM + offx[u] + pre] = t;
        }
        if (which == 0 && b == 0 && tid == 0) out[0] = 0.0f;
    }
}

// ---------------------------------------------------------------------------
// K2 main: ONE block per (b, 32-col tile); 256 thr / 4 waves. No split-K:
// each block streams ALL nx selected rows (gathered via Ridx) against its 32
// staged columns, so column exp-sums, diag dots, logs, and the batch-scaled
// contribution to out[0] all complete in-block. No cross-block state, no
// fences, no gsum. sim2 in log2 units (scale folded into xn).
// ---------------------------------------------------------------------------
__launch_bounds__(256)
__global__ void ntxent_main(const __hip_bfloat16* __restrict__ xn,
                            const __hip_bfloat16* __restrict__ yn,
                            const int* __restrict__ Ridx,
                            const int* __restrict__ Cidx,
                            const int* __restrict__ cnt,
                            float* __restrict__ out, int B) {
    int b  = blockIdx.y;
    int nx = cnt[b];
    int ny = cnt[B + b];
    int m  = min(nx, ny);
    int j0 = blockIdx.x * 32;
    if (j0 >= m) return;

    __shared__ __hip_bfloat16 Bs[32 * 72];   // col-vector stride 144B
    __shared__ float sum_exp[32];
    __shared__ float diag[32];
    __shared__ int   Cloc[32];

    int tid  = threadIdx.x;
    int wave = tid >> 6, lane = tid & 63, quad = lane >> 4, c16 = lane & 15;

    if (tid < 32) {
        int j = j0 + tid;
        Cloc[tid]    = (j < ny) ? Cidx[(size_t)b * T_DIM + j] : 0;
        sum_exp[tid] = 0.0f;
    }
    __syncthreads();

    // Stage B tile: 32 col vectors x 128B = 4.5 KB
    {
        int c = tid >> 3, part = tid & 7;
        bfrag8 v = *reinterpret_cast<const bfrag8*>(
            yn + ((size_t)b * T_DIM + Cloc[c]) * D_DIM + part * 8);
        *reinterpret_cast<bfrag8*>(&Bs[c * 72 + part * 8]) = v;
    }
    __syncthreads();

    bfrag8 bf[2][2];
    #pragma unroll
    for (int cg = 0; cg < 2; cg++)
        #pragma unroll
        for (int kh = 0; kh < 2; kh++)
            bf[cg][kh] = *reinterpret_cast<const bfrag8*>(
                &Bs[(cg * 16 + c16) * 72 + kh * 32 + quad * 8]);

    const __hip_bfloat16* xb = xn + (size_t)b * T_DIM * D_DIM;
    const __hip_bfloat16* yb = yn + (size_t)b * T_DIM * D_DIM;
    const int* Rb = Ridx + (size_t)b * T_DIM;
    const int* Cb = Cidx + (size_t)b * T_DIM;

    // diag dots for this tile's 32 columns (log2 units; xn pre-scaled).
    // 16 groups of 16 lanes; group g does cols g and g+16.
    {
        int g = tid >> 4, l = tid & 15;
        #pragma unroll
        for (int rep = 0; rep < 2; rep++) {
            int c = g + rep * 16;
            int j = j0 + c;
            if (j < m) {
                int rj = Rb[j];
                int cj = Cb[j];
                const unsigned short* xa = (const unsigned short*)(xb + (size_t)rj * D_DIM) + l * 4;
                const unsigned short* yc = (const unsigned short*)(yb + (size_t)cj * D_DIM) + l * 4;
                float d = 0.0f;
                #pragma unroll
                for (int e = 0; e < 4; e++) d += bf2f(xa[e]) * bf2f(yc[e]);
                #pragma unroll
                for (int o = 1; o < 16; o <<= 1) d += __shfl_xor(d, o);
                if (l == 0) diag[c] = d;
            }
        }
    }

    float csum[2] = {0.f, 0.f};

    // prefetch iter 0: index then row (tail rows use row 0, weight 0)
    int gi = wave * 16 + c16;
    int idx0 = (gi < nx) ? Rb[gi] : 0;
    const __hip_bfloat16* arow = xb + (size_t)idx0 * D_DIM;
    bfrag8 af0 = *reinterpret_cast<const bfrag8*>(arow + quad * 8);
    bfrag8 af1 = *reinterpret_cast<const bfrag8*>(arow + 32 + quad * 8);

    for (int i0 = 0; i0 < nx; i0 += 64) {
        int gin = i0 + 64 + wave * 16 + c16;
        int idxn = (gin < nx) ? Rb[gin] : 0;
        const __hip_bfloat16* narow = xb + (size_t)idxn * D_DIM;
        bfrag8 naf0 = *reinterpret_cast<const bfrag8*>(narow + quad * 8);
        bfrag8 naf1 = *reinterpret_cast<const bfrag8*>(narow + 32 + quad * 8);

        int grow0 = i0 + wave * 16 + quad * 4;
        float wv[4];
        #pragma unroll
        for (int r = 0; r < 4; r++) wv[r] = (grow0 + r < nx) ? 1.0f : 0.0f;

        #pragma unroll
        for (int cg = 0; cg < 2; cg++) {
            floatx4 acc = {0.f, 0.f, 0.f, 0.f};
            acc = __builtin_amdgcn_mfma_f32_16x16x32_bf16(af0, bf[cg][0], acc, 0, 0, 0);
            acc = __builtin_amdgcn_mfma_f32_16x16x32_bf16(af1, bf[cg][1], acc, 0, 0, 0);
            #pragma unroll
            for (int r = 0; r < 4; r++)
                csum[cg] += wv[r] * exp2f(acc[r]);
        }
        af0 = naf0; af1 = naf1;
    }

    // reduce over quads (rows): lanes differing in bits 4,5 hold same column
    #pragma unroll
    for (int cg = 0; cg < 2; cg++) {
        csum[cg] += __shfl_xor(csum[cg], 16);
        csum[cg] += __shfl_xor(csum[cg], 32);
    }
    if (lane < 16) {
        atomicAdd(&sum_exp[c16], csum[0]);
        atomicAdd(&sum_exp[16 + c16], csum[1]);
    }
    __syncthreads();

    // wave 0: per-column loss for 32 cols, sum, one global atomicAdd
    if (wave == 0) {
        int c = lane & 31;
        int j = j0 + c;
        float per = (lane < 32 && j < m)
                  ? LN2 * (__log2f(sum_exp[c]) - diag[c]) : 0.0f;
        #pragma unroll
        for (int o = 32; o > 0; o >>= 1) per += __shfl_xor(per, o);
        if (lane == 0)
            atomicAdd(out, per / ((float)m * (float)B));
    }
}

extern "C" void kernel_launch(void* const* d_in, const int* in_sizes, int n_in,
                              void* d_out, int out_size, void* d_ws, size_t ws_size,
                              hipStream_t stream) {
    const float* x  = (const float*)d_in[0];
    const float* y  = (const float*)d_in[1];
    const int* im1  = (const int*)d_in[2];
    const int* im2  = (const int*)d_in[3];
    const int* sh1  = (const int*)d_in[4];
    const int* sh2  = (const int*)d_in[5];

    int B = in_sizes[2] / T_DIM;
    int rows = B * T_DIM;
    size_t nElem = (size_t)rows * D_DIM;

    __hip_bfloat16* xn = (__hip_bfloat16*)d_ws;
    __hip_bfloat16* yn = xn + nElem;
    int*   Ridx = (int*)(yn + nElem);
    int*   Cidx = Ridx + rows;
    int*   cnt  = Cidx + rows;              // 2*B ints

    int normBlocks = 2 * rows / 16;
    prep<<<normBlocks + 2 * B, 256, 0, stream>>>(x, y, im1, sh1, im2, sh2,
                                                 xn, yn, Ridx, Cidx, cnt,
                                                 (float*)d_out, rows, normBlocks, B);

    dim3 grid(T_DIM / 32, B);
    ntxent_main<<<grid, 256, 0, stream>>>(xn, yn, Ridx, Cidx, cnt,
                                          (float*)d_out, B);
}

// Round 8
// 114.942 us; speedup vs baseline: 2.5358x; 1.0137x over previous
//
#include <hip/hip_runtime.h>
#include <hip/hip_bf16.h>
#include <math.h>

#define T_DIM 4096
#define D_DIM 64
#define SCALE_X 14.4269504088896340736f   // (1/TEMPERATURE) * log2(e): exp(10 s) = exp2(14.427 s)
#define LN2 0.69314718055994530942f

typedef short bfrag8 __attribute__((ext_vector_type(8)));   // 8 bf16 = 4 VGPRs
typedef float floatx4 __attribute__((ext_vector_type(4)));

__device__ __forceinline__ float bf2f(unsigned short u) {
    return __uint_as_float(((unsigned int)u) << 16);
}

// ---------------------------------------------------------------------------
// K1 "prep": fused normalize (blocks [0,normBlocks)) + parallel 2-pass mask
// compaction + out zeroing (blocks [normBlocks, normBlocks+2B)).
// Normalize: 16 rows/block, 16 lanes/row, float4 loads, ushort4 stores.
// Rows with combined mask 0 are skipped (never read by main: A-gather and
// B-stage touch only selected rows, and tails are clamped to selected rows).
// x rows scaled by SCALE_X (folds 1/T and log2(e) into the bf16 cast).
// ---------------------------------------------------------------------------
__launch_bounds__(256)
__global__ void prep(const float* __restrict__ x, const float* __restrict__ y,
                     const int* __restrict__ im1, const int* __restrict__ sh1,
                     const int* __restrict__ im2, const int* __restrict__ sh2,
                     __hip_bfloat16* __restrict__ xn, __hip_bfloat16* __restrict__ yn,
                     int* __restrict__ Ridx, int* __restrict__ Cidx,
                     int* __restrict__ cnt, float* __restrict__ out,
                     int rows, int normBlocks, int B) {
    int tid = threadIdx.x;
    if ((int)blockIdx.x < normBlocks) {
        int row = blockIdx.x * 16 + (tid >> 4);
        int l = tid & 15;
        const float* src; __hip_bfloat16* dst; float scale; int sel;
        if (row < rows) {
            src = x; dst = xn; scale = SCALE_X;
            sel = im1[row] * sh1[row];
        } else {
            row -= rows;
            src = y; dst = yn; scale = 1.0f;
            sel = im2[row] * sh2[row];
        }
        if (!sel) return;   // whole 16-lane group exits together
        size_t off = (size_t)row * D_DIM + l * 4;
        float4 v = *reinterpret_cast<const float4*>(src + off);
        float ss = v.x * v.x + v.y * v.y + v.z * v.z + v.w * v.w;
        #pragma unroll
        for (int o = 1; o < 16; o <<= 1) ss += __shfl_xor(ss, o);
        float inv = scale / fmaxf(sqrtf(ss), 1e-12f);
        __hip_bfloat16 h0 = __float2bfloat16(v.x * inv);
        __hip_bfloat16 h1 = __float2bfloat16(v.y * inv);
        __hip_bfloat16 h2 = __float2bfloat16(v.z * inv);
        __hip_bfloat16 h3 = __float2bfloat16(v.w * inv);
        ushort4 o4;
        o4.x = *reinterpret_cast<unsigned short*>(&h0);
        o4.y = *reinterpret_cast<unsigned short*>(&h1);
        o4.z = *reinterpret_cast<unsigned short*>(&h2);
        o4.w = *reinterpret_cast<unsigned short*>(&h3);
        *reinterpret_cast<ushort4*>((unsigned short*)dst + off) = o4;
    } else {
        int z = blockIdx.x - normBlocks;
        int which = z & 1, b = z >> 1;
        const int* im = which ? im2 : im1;
        const int* sh = which ? sh2 : sh1;
        int* idxout   = which ? Cidx : Ridx;

        // 64 wave-units of 64 elements; wave w owns units w, w+4, ..., w+60.
        __shared__ int cw[64];     // per-unit selected count
        __shared__ int offx[64];   // exclusive prefix
        int w = tid >> 6, lane = tid & 63;
        const int* imb = im + (size_t)b * T_DIM;
        const int* shb = sh + (size_t)b * T_DIM;

        // pass 1: parallel counts
        #pragma unroll
        for (int k = 0; k < 16; k++) {
            int u = w + k * 4;
            int t = u * 64 + lane;
            int mv = imb[t] * shb[t];
            unsigned long long bal = __ballot(mv != 0);
            if (lane == 0) cw[u] = __popcll(bal);
        }
        __syncthreads();
        // scan 64 counts on wave 0
        if (w == 0) {
            int v = cw[lane];
            int incl = v;
            #pragma unroll
            for (int o = 1; o < 64; o <<= 1) {
                int t = __shfl_up(incl, o);
                if (lane >= o) incl += t;
            }
            offx[lane] = incl - v;
            if (lane == 63) cnt[which * B + b] = incl;
        }
        __syncthreads();
        // pass 2: parallel writes
        #pragma unroll
        for (int k = 0; k < 16; k++) {
            int u = w + k * 4;
            int t = u * 64 + lane;
            int mv = imb[t] * shb[t];
            unsigned long long bal = __ballot(mv != 0);
            int pre = __popcll(bal & ((1ull << lane) - 1ull));
            if (mv) idxout[(size_t)b * T_DIM + offx[u] + pre] = t;
        }
        if (which == 0 && b == 0 && tid == 0) out[0] = 0.0f;
    }
}

// ---------------------------------------------------------------------------
// K2 main: ONE block per (b, 32-col tile); 512 thr / 8 WAVES, rows split
// across waves (each iter covers 128 rows -> ~16 serial iters at nx~2048,
// 16 waves/CU at 2 blocks/CU for latency hiding). Column exp-sums, diag
// dots, logs, and the batch-scaled contribution to out[0] all complete
// in-block; no cross-block state, no fences. sim2 in log2 units.
// ---------------------------------------------------------------------------
__launch_bounds__(512)
__global__ void ntxent_main(const __hip_bfloat16* __restrict__ xn,
                            const __hip_bfloat16* __restrict__ yn,
                            const int* __restrict__ Ridx,
                            const int* __restrict__ Cidx,
                            const int* __restrict__ cnt,
                            float* __restrict__ out, int B) {
    int b  = blockIdx.y;
    int nx = cnt[b];
    int ny = cnt[B + b];
    int m  = min(nx, ny);
    int j0 = blockIdx.x * 32;
    if (j0 >= m) return;

    __shared__ __hip_bfloat16 Bs[32 * 72];   // col-vector stride 144B
    __shared__ float sum_exp[32];
    __shared__ float diag[32];
    __shared__ int   Cloc[32];

    int tid  = threadIdx.x;
    int wave = tid >> 6, lane = tid & 63, quad = lane >> 4, c16 = lane & 15;

    if (tid < 32) {
        int j = j0 + tid;
        Cloc[tid]    = (j < ny) ? Cidx[(size_t)b * T_DIM + j] : 0;
        sum_exp[tid] = 0.0f;
    }
    __syncthreads();

    // Stage B tile: 32 col vectors x 128B = 4.5 KB (first 256 threads)
    if (tid < 256) {
        int c = tid >> 3, part = tid & 7;
        bfrag8 v = *reinterpret_cast<const bfrag8*>(
            yn + ((size_t)b * T_DIM + Cloc[c]) * D_DIM + part * 8);
        *reinterpret_cast<bfrag8*>(&Bs[c * 72 + part * 8]) = v;
    }
    __syncthreads();

    bfrag8 bf[2][2];
    #pragma unroll
    for (int cg = 0; cg < 2; cg++)
        #pragma unroll
        for (int kh = 0; kh < 2; kh++)
            bf[cg][kh] = *reinterpret_cast<const bfrag8*>(
                &Bs[(cg * 16 + c16) * 72 + kh * 32 + quad * 8]);

    const __hip_bfloat16* xb = xn + (size_t)b * T_DIM * D_DIM;
    const __hip_bfloat16* yb = yn + (size_t)b * T_DIM * D_DIM;
    const int* Rb = Ridx + (size_t)b * T_DIM;
    const int* Cb = Cidx + (size_t)b * T_DIM;

    // diag dots for this tile's 32 columns (log2 units; xn pre-scaled).
    // 32 groups of 16 lanes; group g does col g.
    {
        int g = tid >> 4, l = tid & 15;
        int j = j0 + g;
        if (j < m) {
            int rj = Rb[j];
            int cj = Cb[j];
            const unsigned short* xa = (const unsigned short*)(xb + (size_t)rj * D_DIM) + l * 4;
            const unsigned short* yc = (const unsigned short*)(yb + (size_t)cj * D_DIM) + l * 4;
            float d = 0.0f;
            #pragma unroll
            for (int e = 0; e < 4; e++) d += bf2f(xa[e]) * bf2f(yc[e]);
            #pragma unroll
            for (int o = 1; o < 16; o <<= 1) d += __shfl_xor(d, o);
            if (l == 0) diag[g] = d;
        }
    }

    float csum[2] = {0.f, 0.f};

    // prefetch iter 0 (tail indices clamped to Rb[nx-1]: valid, normalized)
    int gi = wave * 16 + c16;
    int idx0 = Rb[min(gi, nx - 1)];
    const __hip_bfloat16* arow = xb + (size_t)idx0 * D_DIM;
    bfrag8 af0 = *reinterpret_cast<const bfrag8*>(arow + quad * 8);
    bfrag8 af1 = *reinterpret_cast<const bfrag8*>(arow + 32 + quad * 8);

    for (int i0 = 0; i0 < nx; i0 += 128) {
        int gin = i0 + 128 + wave * 16 + c16;
        int idxn = Rb[min(gin, nx - 1)];
        const __hip_bfloat16* narow = xb + (size_t)idxn * D_DIM;
        bfrag8 naf0 = *reinterpret_cast<const bfrag8*>(narow + quad * 8);
        bfrag8 naf1 = *reinterpret_cast<const bfrag8*>(narow + 32 + quad * 8);

        int grow0 = i0 + wave * 16 + quad * 4;
        float wv[4];
        #pragma unroll
        for (int r = 0; r < 4; r++) wv[r] = (grow0 + r < nx) ? 1.0f : 0.0f;

        #pragma unroll
        for (int cg = 0; cg < 2; cg++) {
            floatx4 acc = {0.f, 0.f, 0.f, 0.f};
            acc = __builtin_amdgcn_mfma_f32_16x16x32_bf16(af0, bf[cg][0], acc, 0, 0, 0);
            acc = __builtin_amdgcn_mfma_f32_16x16x32_bf16(af1, bf[cg][1], acc, 0, 0, 0);
            #pragma unroll
            for (int r = 0; r < 4; r++)
                csum[cg] += wv[r] * exp2f(acc[r]);
        }
        af0 = naf0; af1 = naf1;
    }

    // reduce over quads (rows) within the wave, then merge waves in LDS
    #pragma unroll
    for (int cg = 0; cg < 2; cg++) {
        csum[cg] += __shfl_xor(csum[cg], 16);
        csum[cg] += __shfl_xor(csum[cg], 32);
    }
    if (lane < 16) {
        atomicAdd(&sum_exp[c16], csum[0]);
        atomicAdd(&sum_exp[16 + c16], csum[1]);
    }
    __syncthreads();

    // wave 0: per-column loss for 32 cols, sum, one global atomicAdd
    if (wave == 0) {
        int c = lane & 31;
        int j = j0 + c;
        float per = (lane < 32 && j < m)
                  ? LN2 * (__log2f(sum_exp[c]) - diag[c]) : 0.0f;
        #pragma unroll
        for (int o = 32; o > 0; o >>= 1) per += __shfl_xor(per, o);
        if (lane == 0)
            atomicAdd(out, per / ((float)m * (float)B));
    }
}

extern "C" void kernel_launch(void* const* d_in, const int* in_sizes, int n_in,
                              void* d_out, int out_size, void* d_ws, size_t ws_size,
                              hipStream_t stream) {
    const float* x  = (const float*)d_in[0];
    const float* y  = (const float*)d_in[1];
    const int* im1  = (const int*)d_in[2];
    const int* im2  = (const int*)d_in[3];
    const int* sh1  = (const int*)d_in[4];
    const int* sh2  = (const int*)d_in[5];

    int B = in_sizes[2] / T_DIM;
    int rows = B * T_DIM;
    size_t nElem = (size_t)rows * D_DIM;

    __hip_bfloat16* xn = (__hip_bfloat16*)d_ws;
    __hip_bfloat16* yn = xn + nElem;
    int*   Ridx = (int*)(yn + nElem);
    int*   Cidx = Ridx + rows;
    int*   cnt  = Cidx + rows;              // 2*B ints

    int normBlocks = 2 * rows / 16;
    prep<<<normBlocks + 2 * B, 256, 0, stream>>>(x, y, im1, sh1, im2, sh2,
                                                 xn, yn, Ridx, Cidx, cnt,
                                                 (float*)d_out, rows, normBlocks, B);

    dim3 grid(T_DIM / 32, B);
    ntxent_main<<<grid, 512, 0, stream>>>(xn, yn, Ridx, Cidx, cnt,
                                          (float*)d_out, B);
}